// Round 1
// baseline (444.898 us; speedup 1.0000x reference)
//
#include <hip/hip_runtime.h>
#include <hip/hip_bf16.h>
#include <cstdint>

// Problem constants
#define TOKENS 8192
#define DIM 4096
#define D4 (DIM / 4)      // 1024 float4 per row
#define NEXP 8
#define TOPK 2
#define SLOTS (TOKENS * TOPK)   // 16384
#define NCHUNK (SLOTS / 64)     // 256 chunks of 64 slots

// Output layout (all fp32, concatenated in reference return order)
#define OUT_X 0
#define OUT_CNT ((size_t)TOKENS * TOPK * DIM)            // 67108864
#define OUT_SCAT (OUT_CNT + NEXP)                        // 67108872
#define OUT_SCORE (OUT_SCAT + SLOTS)                     // 67125256

// ---------------------------------------------------------------------------
// Kernel 1: scores = x @ W^T, top-2, softmax over the 2 scores.
// 4 waves / block, 8 tokens / wave. W chunk held in registers, reused
// across the wave's 8 tokens -> W L2 traffic = 16KB*8 per 8 tokens.
// ---------------------------------------------------------------------------
__global__ __launch_bounds__(256) void k_score(const float* __restrict__ x,
                                               const float* __restrict__ W,
                                               int* __restrict__ eid,
                                               float* __restrict__ prob)
{
    const int wave = threadIdx.x >> 6;
    const int lane = threadIdx.x & 63;
    const int tok0 = (blockIdx.x * 4 + wave) * 8;

    const float4* x4 = reinterpret_cast<const float4*>(x);
    const float4* W4 = reinterpret_cast<const float4*>(W);

    float acc[8][NEXP];
#pragma unroll
    for (int t = 0; t < 8; ++t)
#pragma unroll
        for (int e = 0; e < NEXP; ++e) acc[t][e] = 0.f;

    for (int i = 0; i < 16; ++i) {
        const int d4 = lane + 64 * i;
        float4 w[NEXP];
#pragma unroll
        for (int e = 0; e < NEXP; ++e) w[e] = W4[e * D4 + d4];
#pragma unroll
        for (int t = 0; t < 8; ++t) {
            const float4 xv = x4[(size_t)(tok0 + t) * D4 + d4];
#pragma unroll
            for (int e = 0; e < NEXP; ++e) {
                acc[t][e] = fmaf(xv.x, w[e].x, acc[t][e]);
                acc[t][e] = fmaf(xv.y, w[e].y, acc[t][e]);
                acc[t][e] = fmaf(xv.z, w[e].z, acc[t][e]);
                acc[t][e] = fmaf(xv.w, w[e].w, acc[t][e]);
            }
        }
    }

    // Cross-lane butterfly reduce: afterwards every lane holds the full sum
    // for every (t,e). Compile-time indexing only (no VGPR indexing).
#pragma unroll
    for (int t = 0; t < 8; ++t)
#pragma unroll
        for (int e = 0; e < NEXP; ++e) {
            float v = acc[t][e];
#pragma unroll
            for (int off = 32; off >= 1; off >>= 1) v += __shfl_xor(v, off);
            acc[t][e] = v;
        }

    // Top-2 + softmax; computed redundantly on all lanes (cheap), lane t writes.
#pragma unroll
    for (int t = 0; t < 8; ++t) {
        int i0 = 0;
        float m0 = acc[t][0];
#pragma unroll
        for (int e = 1; e < NEXP; ++e)
            if (acc[t][e] > m0) { m0 = acc[t][e]; i0 = e; }  // strict > keeps lowest idx on tie
        int i1 = -1;
        float m1 = -INFINITY;
#pragma unroll
        for (int e = 0; e < NEXP; ++e)
            if (e != i0 && acc[t][e] > m1) { m1 = acc[t][e]; i1 = e; }
        const float z = __expf(m1 - m0);   // <= 1
        const float inv = 1.0f / (1.0f + z);
        if (lane == t) {
            const int s2 = (tok0 + t) * 2;
            eid[s2] = i0;
            eid[s2 + 1] = i1;
            prob[s2] = inv;          // softmax of the max score
            prob[s2 + 1] = z * inv;  // softmax of the 2nd score
        }
    }
}

// ---------------------------------------------------------------------------
// Kernel 2: stable counting sort of 16384 (expert, slot) pairs. Single block.
// Phase A: per-64-slot chunk histograms via ballot.
// Phase B: wave 0 scans 256 chunks x 8 experts -> exclusive bases + totals.
// Phase C: rank within chunk via ballot & lanemask_lt; emit positions,
//          counts, scatter_indices, scores_sorted.
// ---------------------------------------------------------------------------
__global__ __launch_bounds__(1024) void k_sort(const int* __restrict__ eid,
                                               const float* __restrict__ prob,
                                               int* __restrict__ dstpos,
                                               float* __restrict__ out)
{
    __shared__ int hist[NCHUNK][NEXP];  // counts, then exclusive bases
    const int tid = threadIdx.x;
    const int wave = tid >> 6;
    const int lane = tid & 63;

    // Phase A
    for (int c = wave; c < NCHUNK; c += 16) {
        const int s = c * 64 + lane;
        const int e = eid[s];
#pragma unroll
        for (int q = 0; q < NEXP; ++q) {
            const unsigned long long m = __ballot(e == q);
            if (lane == q) hist[c][q] = __popcll(m);
        }
    }
    __syncthreads();

    // Phase B (wave 0 only)
    if (wave == 0) {
        int run[NEXP];
#pragma unroll
        for (int q = 0; q < NEXP; ++q) run[q] = 0;

        for (int r = 0; r < 4; ++r) {
            const int c = r * 64 + lane;
#pragma unroll
            for (int q = 0; q < NEXP; ++q) {
                const int v = hist[c][q];
                int incl = v;
#pragma unroll
                for (int off = 1; off <= 32; off <<= 1) {
                    const int n = __shfl_up(incl, off);
                    if (lane >= off) incl += n;
                }
                hist[c][q] = run[q] + incl - v;          // exclusive prefix within expert stream
                run[q] += __shfl(incl, 63);              // uniform update
            }
        }
        // run[q] = total tokens routed to expert q (uniform across wave 0)
        int eoff[NEXP];
        int a = 0;
#pragma unroll
        for (int q = 0; q < NEXP; ++q) { eoff[q] = a; a += run[q]; }
        for (int r = 0; r < 4; ++r) {
            const int c = r * 64 + lane;
#pragma unroll
            for (int q = 0; q < NEXP; ++q) hist[c][q] += eoff[q];
        }
        if (lane == 0) {
#pragma unroll
            for (int q = 0; q < NEXP; ++q) out[OUT_CNT + q] = (float)run[q];
        }
    }
    __syncthreads();

    // Phase C
    for (int c = wave; c < NCHUNK; c += 16) {
        const int s = c * 64 + lane;
        const int e = eid[s];
        const unsigned long long lt = (1ull << lane) - 1ull;
        int rank = 0;
#pragma unroll
        for (int q = 0; q < NEXP; ++q) {
            const unsigned long long m = __ballot(e == q);
            if (e == q) rank = __popcll(m & lt);
        }
        const int p = hist[c][e] + rank;
        dstpos[s] = p;
        out[OUT_SCAT + p] = (float)(s >> 1);   // sorted_indices // 2 = token id
        out[OUT_SCORE + p] = prob[s];
    }
}

// ---------------------------------------------------------------------------
// Kernel 3: gather. One block per token; read x row once, write to both
// destination rows (top-2 experts are always distinct).
// ---------------------------------------------------------------------------
__global__ __launch_bounds__(256) void k_gather(const float* __restrict__ x,
                                                const int* __restrict__ dstpos,
                                                float* __restrict__ out)
{
    const int t = blockIdx.x;
    const int p0 = dstpos[t * 2];
    const int p1 = dstpos[t * 2 + 1];
    const float4* x4 = reinterpret_cast<const float4*>(x) + (size_t)t * D4;
    float4* o4 = reinterpret_cast<float4*>(out);
#pragma unroll
    for (int i = 0; i < 4; ++i) {
        const int idx = threadIdx.x + 256 * i;
        const float4 v = x4[idx];
        o4[(size_t)p0 * D4 + idx] = v;
        o4[(size_t)p1 * D4 + idx] = v;
    }
}

extern "C" void kernel_launch(void* const* d_in, const int* in_sizes, int n_in,
                              void* d_out, int out_size, void* d_ws, size_t ws_size,
                              hipStream_t stream)
{
    const float* x = (const float*)d_in[0];
    const float* W = (const float*)d_in[1];
    float* out = (float*)d_out;

    // Workspace: eid[16384] int | prob[16384] float | dstpos[16384] int = 192 KB
    int* eid = (int*)d_ws;
    float* prob = (float*)((char*)d_ws + 64 * 1024);
    int* dstpos = (int*)((char*)d_ws + 128 * 1024);

    k_score<<<TOKENS / 32, 256, 0, stream>>>(x, W, eid, prob);
    k_sort<<<1, 1024, 0, stream>>>(eid, prob, dstpos, out);
    k_gather<<<TOKENS, 256, 0, stream>>>(x, dstpos, out);
}

// Round 3
// 389.033 us; speedup vs baseline: 1.1436x; 1.1436x over previous
//
#include <hip/hip_runtime.h>
#include <hip/hip_bf16.h>
#include <cstdint>

// Problem constants
#define TOKENS 8192
#define DIM 4096
#define D4 (DIM / 4)      // 1024 float4 per row
#define NEXP 8
#define TOPK 2
#define SLOTS (TOKENS * TOPK)   // 16384
#define NCHUNK (SLOTS / 64)     // 256 chunks of 64 slots

// Output layout (all fp32, concatenated in reference return order)
#define OUT_CNT ((size_t)TOKENS * TOPK * DIM)            // 67108864
#define OUT_SCAT (OUT_CNT + NEXP)                        // 67108872
#define OUT_SCORE (OUT_SCAT + SLOTS)                     // 67125256

// Native clang vector (required by __builtin_nontemporal_store)
typedef float vfloat4 __attribute__((ext_vector_type(4)));

// ---------------------------------------------------------------------------
// Kernel 1: scores = x @ W^T, top-2, softmax over the 2 selected scores.
// 4 tokens / wave, 4 waves / block, 512 blocks (2 blocks/CU, 8 waves/CU).
// e-outer inner loop: only ONE W float4 live at a time.
// VGPR budget: acc[4][8]=32 + xv[4]=16 + w=4 + addr ≈ 70 — no spill.
// ---------------------------------------------------------------------------
__global__ __launch_bounds__(256) void k_score(const float* __restrict__ x,
                                               const float* __restrict__ W,
                                               int* __restrict__ eid,
                                               float* __restrict__ prob)
{
    const int wave = threadIdx.x >> 6;
    const int lane = threadIdx.x & 63;
    const int tok0 = (blockIdx.x * 4 + wave) * 4;

    const float4* x4 = reinterpret_cast<const float4*>(x);
    const float4* W4 = reinterpret_cast<const float4*>(W);

    float acc[4][NEXP];
#pragma unroll
    for (int t = 0; t < 4; ++t)
#pragma unroll
        for (int e = 0; e < NEXP; ++e) acc[t][e] = 0.f;

    for (int i = 0; i < 16; ++i) {
        const int d4 = lane + 64 * i;
        float4 xv[4];
#pragma unroll
        for (int t = 0; t < 4; ++t) xv[t] = x4[(size_t)(tok0 + t) * D4 + d4];
#pragma unroll
        for (int e = 0; e < NEXP; ++e) {
            const float4 w = W4[e * D4 + d4];
#pragma unroll
            for (int t = 0; t < 4; ++t) {
                acc[t][e] = fmaf(xv[t].x, w.x, acc[t][e]);
                acc[t][e] = fmaf(xv[t].y, w.y, acc[t][e]);
                acc[t][e] = fmaf(xv[t].z, w.z, acc[t][e]);
                acc[t][e] = fmaf(xv[t].w, w.w, acc[t][e]);
            }
        }
    }

    // Cross-lane butterfly reduce (compile-time indexing only).
#pragma unroll
    for (int t = 0; t < 4; ++t)
#pragma unroll
        for (int e = 0; e < NEXP; ++e) {
            float v = acc[t][e];
#pragma unroll
            for (int off = 32; off >= 1; off >>= 1) v += __shfl_xor(v, off);
            acc[t][e] = v;
        }

    // Top-2 + softmax; redundant on all lanes, lane t writes token t.
#pragma unroll
    for (int t = 0; t < 4; ++t) {
        int i0 = 0;
        float m0 = acc[t][0];
#pragma unroll
        for (int e = 1; e < NEXP; ++e)
            if (acc[t][e] > m0) { m0 = acc[t][e]; i0 = e; }  // strict > keeps lowest idx
        int i1 = -1;
        float m1 = -INFINITY;
#pragma unroll
        for (int e = 0; e < NEXP; ++e)
            if (e != i0 && acc[t][e] > m1) { m1 = acc[t][e]; i1 = e; }
        const float z = __expf(m1 - m0);   // <= 1
        const float inv = 1.0f / (1.0f + z);
        if (lane == t) {
            const int s2 = (tok0 + t) * 2;
            eid[s2] = i0;
            eid[s2 + 1] = i1;
            prob[s2] = inv;
            prob[s2 + 1] = z * inv;
        }
    }
}

// ---------------------------------------------------------------------------
// Sort phase A: per-64-slot chunk histograms via ballot. One wave per chunk.
// ---------------------------------------------------------------------------
__global__ __launch_bounds__(64) void k_hist(const int* __restrict__ eid,
                                             int* __restrict__ hist)
{
    const int c = blockIdx.x;
    const int lane = threadIdx.x;
    const int e = eid[c * 64 + lane];
#pragma unroll
    for (int q = 0; q < NEXP; ++q) {
        const unsigned long long m = __ballot(e == q);
        if (lane == q) hist[c * NEXP + q] = __popcll(m);
    }
}

// ---------------------------------------------------------------------------
// Sort phase B: one wave scans 256 chunks x 8 experts -> exclusive global
// bases (written back into hist) + per-expert totals (written to out counts).
// ---------------------------------------------------------------------------
__global__ __launch_bounds__(64) void k_scan(int* __restrict__ hist,
                                             float* __restrict__ out)
{
    const int lane = threadIdx.x;
    int run[NEXP];
#pragma unroll
    for (int q = 0; q < NEXP; ++q) run[q] = 0;

    int excl[4][NEXP];   // exclusive-within-expert-stream prefix for chunk r*64+lane
    for (int r = 0; r < 4; ++r) {
        const int c = r * 64 + lane;
#pragma unroll
        for (int q = 0; q < NEXP; ++q) {
            const int v = hist[c * NEXP + q];
            int incl = v;
#pragma unroll
            for (int off = 1; off <= 32; off <<= 1) {
                const int n = __shfl_up(incl, off);
                if (lane >= off) incl += n;
            }
            excl[r][q] = run[q] + incl - v;
            run[q] += __shfl(incl, 63);   // uniform
        }
    }
    // expert base offsets
    int eoff[NEXP];
    int a = 0;
#pragma unroll
    for (int q = 0; q < NEXP; ++q) { eoff[q] = a; a += run[q]; }
    for (int r = 0; r < 4; ++r) {
        const int c = r * 64 + lane;
#pragma unroll
        for (int q = 0; q < NEXP; ++q) hist[c * NEXP + q] = excl[r][q] + eoff[q];
    }
    if (lane == 0) {
#pragma unroll
        for (int q = 0; q < NEXP; ++q) out[OUT_CNT + q] = (float)run[q];
    }
}

// ---------------------------------------------------------------------------
// Sort phase C: rank within chunk via ballot; emit destination positions,
// scatter_indices, scores_sorted. One wave per chunk.
// ---------------------------------------------------------------------------
__global__ __launch_bounds__(64) void k_pos(const int* __restrict__ eid,
                                            const float* __restrict__ prob,
                                            const int* __restrict__ hist,
                                            int* __restrict__ dstpos,
                                            float* __restrict__ out)
{
    const int c = blockIdx.x;
    const int lane = threadIdx.x;
    const int s = c * 64 + lane;
    const int e = eid[s];
    const unsigned long long lt = (1ull << lane) - 1ull;
    int rank = 0;
#pragma unroll
    for (int q = 0; q < NEXP; ++q) {
        const unsigned long long m = __ballot(e == q);
        if (e == q) rank = __popcll(m & lt);
    }
    const int p = hist[c * NEXP + e] + rank;
    dstpos[s] = p;
    out[OUT_SCAT + p] = (float)(s >> 1);   // sorted_indices // 2 = token id
    out[OUT_SCORE + p] = prob[s];
}

// ---------------------------------------------------------------------------
// Kernel 5: gather. One block per token; read x row once (L3-warm), write to
// both destination rows with nontemporal stores (don't evict x from L3).
// ---------------------------------------------------------------------------
__global__ __launch_bounds__(256) void k_gather(const float* __restrict__ x,
                                                const int* __restrict__ dstpos,
                                                float* __restrict__ out)
{
    const int t = blockIdx.x;
    const int p0 = dstpos[t * 2];
    const int p1 = dstpos[t * 2 + 1];
    const vfloat4* x4 = reinterpret_cast<const vfloat4*>(x) + (size_t)t * D4;
    vfloat4* o4 = reinterpret_cast<vfloat4*>(out);
#pragma unroll
    for (int i = 0; i < 4; ++i) {
        const int idx = threadIdx.x + 256 * i;
        const vfloat4 v = x4[idx];
        __builtin_nontemporal_store(v, &o4[(size_t)p0 * D4 + idx]);
        __builtin_nontemporal_store(v, &o4[(size_t)p1 * D4 + idx]);
    }
}

extern "C" void kernel_launch(void* const* d_in, const int* in_sizes, int n_in,
                              void* d_out, int out_size, void* d_ws, size_t ws_size,
                              hipStream_t stream)
{
    const float* x = (const float*)d_in[0];
    const float* W = (const float*)d_in[1];
    float* out = (float*)d_out;

    // Workspace: eid[16384] int | prob[16384] float | dstpos[16384] int | hist[256*8] int
    int* eid = (int*)d_ws;
    float* prob = (float*)((char*)d_ws + 64 * 1024);
    int* dstpos = (int*)((char*)d_ws + 128 * 1024);
    int* hist = (int*)((char*)d_ws + 192 * 1024);

    k_score<<<TOKENS / 16, 256, 0, stream>>>(x, W, eid, prob);
    k_hist<<<NCHUNK, 64, 0, stream>>>(eid, hist);
    k_scan<<<1, 64, 0, stream>>>(hist, out);
    k_pos<<<NCHUNK, 64, 0, stream>>>(eid, prob, hist, dstpos, out);
    k_gather<<<TOKENS, 256, 0, stream>>>(x, dstpos, out);
}